// Round 3
// baseline (382.633 us; speedup 1.0000x reference)
//
#include <hip/hip_runtime.h>
#include <hip/hip_bf16.h>
#include <math.h>

typedef unsigned short u16;
typedef short s16x8 __attribute__((ext_vector_type(8)));
typedef float f32x4 __attribute__((ext_vector_type(4)));
typedef unsigned u32x4 __attribute__((ext_vector_type(4)));

// k-interleave within a 32-wide k-tile: lane's contiguous 16B = [4g..4g+3, 16+4g..16+4g+3]
__device__ __host__ __forceinline__ int KP(int k) {
    return (((k) & 12) << 1) | ((((k) >> 4) & 1) << 2) | ((k) & 3);
}

__device__ __forceinline__ float geluf(float x) {
    return 0.5f * x * (1.0f + erff(x * 0.70710678118654752f));
}
__device__ __forceinline__ u16 f2bf(float f) {
    unsigned u = __builtin_bit_cast(unsigned, f);
    return (u16)((u + 0x7fffu + ((u >> 16) & 1u)) >> 16);
}
__device__ __forceinline__ float bf2f(u16 h) {
    return __builtin_bit_cast(float, ((unsigned)h) << 16);
}
__device__ __forceinline__ void async_copy16(const u16* gsrc, u16* ldst) {
    __builtin_amdgcn_global_load_lds((const __attribute__((address_space(1))) void*)gsrc,
                                     (__attribute__((address_space(3))) void*)ldst, 16, 0, 0);
}

// packed-bf16 |q-k| (truncating round; error <= 2^-8 rel, washes out)
__device__ __forceinline__ s16x8 feat_abs(s16x8 k, s16x8 q) {
    u32x4 kk = __builtin_bit_cast(u32x4, k), qq = __builtin_bit_cast(u32x4, q);
    u32x4 o;
    #pragma unroll
    for (int p = 0; p < 4; ++p) {
        unsigned kp = kk[p], qp = qq[p];
        float klo = __builtin_bit_cast(float, kp << 16);
        float khi = __builtin_bit_cast(float, kp & 0xFFFF0000u);
        float qlo = __builtin_bit_cast(float, qp << 16);
        float qhi = __builtin_bit_cast(float, qp & 0xFFFF0000u);
        unsigned dlo = __builtin_bit_cast(unsigned, qlo - klo) & 0x7FFFFFFFu;
        unsigned dhi = __builtin_bit_cast(unsigned, qhi - khi) & 0x7FFFFFFFu;
        o[p] = (dhi & 0xFFFF0000u) | (dlo >> 16);
    }
    return __builtin_bit_cast(s16x8, o);
}
// packed-bf16 q*k
__device__ __forceinline__ s16x8 feat_mul(s16x8 k, s16x8 q) {
    u32x4 kk = __builtin_bit_cast(u32x4, k), qq = __builtin_bit_cast(u32x4, q);
    u32x4 o;
    #pragma unroll
    for (int p = 0; p < 4; ++p) {
        unsigned kp = kk[p], qp = qq[p];
        float klo = __builtin_bit_cast(float, kp << 16);
        float khi = __builtin_bit_cast(float, kp & 0xFFFF0000u);
        float qlo = __builtin_bit_cast(float, qp << 16);
        float qhi = __builtin_bit_cast(float, qp & 0xFFFF0000u);
        unsigned plo = __builtin_bit_cast(unsigned, qlo * klo);
        unsigned phi = __builtin_bit_cast(unsigned, qhi * khi);
        o[p] = (phi & 0xFFFF0000u) | (plo >> 16);
    }
    return __builtin_bit_cast(s16x8, o);
}

__device__ __forceinline__ float wave_reduce_sum(float v) {
    #pragma unroll
    for (int m = 32; m >= 1; m >>= 1) v += __shfl_xor(v, m, 64);
    return v;
}

// ---------- prep: W[K][N] fp32 -> blocked bf16 B-tiles [CB cols][32 k]
__global__ __launch_bounds__(256) void prep_w(const float* __restrict__ W, u16* __restrict__ out,
                                              int K, int N, int CB) {
    int idx = blockIdx.x * 256 + threadIdx.x;
    if (idx >= K * N) return;
    int k = idx / N, col = idx % N;
    int cb = col / CB, ci = col % CB, kt = k >> 5, ki = k & 31;
    size_t pos = ((size_t)(cb * (K >> 5) + kt) * CB + ci) * 32 + KP(ki);
    out[pos] = f2bf(W[idx]);
}

// ---------- prep W1 feature blocks (rows 128..511) -> [f*4+dt][256 cols][32]
__global__ __launch_bounds__(256) void prep_w1(const float* __restrict__ W1, u16* __restrict__ out) {
    int idx = blockIdx.x * 256 + threadIdx.x;   // over 384*256
    if (idx >= 384 * 256) return;
    int k = idx / 256 + 128, col = idx % 256;
    int f = (k >> 7) - 1, dt = (k >> 5) & 3, ki = k & 31;
    out[((size_t)((f * 4 + dt) * 256) + col) * 32 + KP(ki)] = f2bf(W1[(size_t)k * 256 + col]);
}

// ---------- nf = LN(ent + role_emb[roles]) -> blocked bf16 tiles [128][32]
__global__ __launch_bounds__(256) void nf_ln_kernel(
    const float* __restrict__ ent, const int* __restrict__ roles,
    const float* __restrict__ role_emb, const float* __restrict__ g,
    const float* __restrict__ bta, u16* __restrict__ nfb)
{
    int wave = threadIdx.x >> 6, lane = threadIdx.x & 63;
    int row = blockIdx.x * 4 + wave;
    const float* er = ent + (size_t)row * 768;
    const float* rr = role_emb + roles[row] * 768;
    float x[12]; float s = 0.f, s2 = 0.f;
    #pragma unroll
    for (int i = 0; i < 12; ++i) {
        x[i] = er[i * 64 + lane] + rr[i * 64 + lane];
        s += x[i]; s2 += x[i] * x[i];
    }
    s = wave_reduce_sum(s); s2 = wave_reduce_sum(s2);
    float mu = s * (1.f / 768.f);
    float var = s2 * (1.f / 768.f) - mu * mu;
    float rs = rsqrtf(var + 1e-5f);
    size_t rb = (size_t)(row >> 7) * 24;
    int rin = row & 127;
    #pragma unroll
    for (int i = 0; i < 12; ++i) {
        int k = i * 64 + lane;
        float v = (x[i] - mu) * rs * g[k] + bta[k];
        size_t pos = (rb + (k >> 5)) * 4096 + (size_t)rin * 32 + KP(k & 31);
        nfb[pos] = f2bf(v);
    }
}

// ---------- q = gelu(q_emb @ Wq + bq) -> bf16 [64][1024]
__global__ __launch_bounds__(256) void q_kernel(
    const float* __restrict__ q_emb, const float* __restrict__ Wq,
    const float* __restrict__ bq, u16* __restrict__ qout)
{
    __shared__ float sq[768];
    int b = blockIdx.y;
    int col = blockIdx.x * 256 + threadIdx.x;
    for (int i = threadIdx.x; i < 768; i += 256) sq[i] = q_emb[b * 768 + i];
    __syncthreads();
    float acc = 0.f;
    #pragma unroll 4
    for (int k = 0; k < 768; ++k) acc = fmaf(sq[k], Wq[(size_t)k * 1024 + col], acc);
    qout[b * 1024 + col] = f2bf(geluf(acc + bq[col]));
}

// ---------- qW1[b,h,:] = q[b,h,:] @ W1[0:128,:] + b1  (f32 [512][256])
__global__ __launch_bounds__(256) void qw1_kernel(
    const u16* __restrict__ qbuf, const float* __restrict__ W1,
    const float* __restrict__ b1, float* __restrict__ qw1)
{
    __shared__ float sq[128];
    int bh = blockIdx.x;      // b*8+h
    int col = threadIdx.x;    // 0..255
    if (col < 128) sq[col] = bf2f(qbuf[bh * 128 + col]);
    __syncthreads();
    float acc = b1[col];
    #pragma unroll 4
    for (int d = 0; d < 128; ++d) acc = fmaf(sq[d], W1[d * 256 + col], acc);
    qw1[bh * 256 + col] = acc;
}

#define MFMA(a, b, c) __builtin_amdgcn_mfma_f32_16x16x32_bf16(a, b, c, 0, 0, 0)

// ---------- kgemm: nf[8192x768] @ Wk[768x1024], gelu -> kblk blocked [rt][dt][64][32]
__global__ __launch_bounds__(256) void kgemm(
    const u16* __restrict__ gA, const u16* __restrict__ gB,
    const float* __restrict__ bias, u16* __restrict__ kblk)
{
    __shared__ __attribute__((aligned(16))) u16 As[2][128 * 32];
    __shared__ __attribute__((aligned(16))) u16 Bs[2][128 * 32];
    const int tid = threadIdx.x, lane = tid & 63, w = tid >> 6;
    const int lr = lane & 15, g = lane >> 4;
    const int wr = w >> 1, wc = w & 1;
    const int nb = blockIdx.x, mb = blockIdx.y;   // 8 x 64
    const int NT = 24;
    f32x4 acc[4][4];
    #pragma unroll
    for (int i = 0; i < 4; ++i)
        #pragma unroll
        for (int j = 0; j < 4; ++j) acc[i][j] = (f32x4){0.f, 0.f, 0.f, 0.f};

    auto stage = [&](int t, int bi) {
        const u16* ab = gA + (size_t)(mb * 24 + t) * 4096;
        const u16* bb = gB + (size_t)(nb * 24 + t) * 4096;
        #pragma unroll
        for (int c = w; c < 16; c += 4) {
            if (c < 8) async_copy16(ab + c * 512 + lane * 8, &As[bi][c * 512]);
            else       async_copy16(bb + (c - 8) * 512 + lane * 8, &Bs[bi][(c - 8) * 512]);
        }
    };
    stage(0, 0);
    __syncthreads();
    for (int t = 0; t < NT; ++t) {
        int cur = t & 1;
        if (t + 1 < NT) stage(t + 1, cur ^ 1);
        s16x8 af[4], bfr[4];
        #pragma unroll
        for (int i = 0; i < 4; ++i) af[i] = *(const s16x8*)&As[cur][(wr * 64 + i * 16 + lr) * 32 + g * 8];
        #pragma unroll
        for (int j = 0; j < 4; ++j) bfr[j] = *(const s16x8*)&Bs[cur][(wc * 64 + j * 16 + lr) * 32 + g * 8];
        #pragma unroll
        for (int i = 0; i < 4; ++i)
            #pragma unroll
            for (int j = 0; j < 4; ++j) acc[i][j] = MFMA(af[i], bfr[j], acc[i][j]);
        __syncthreads();
    }
    // epilogue: gelu, write blocked layout for h1 (row_glob = b*1024 + n*8 + h; b=mb, h=nb)
    float bkc[4];
    #pragma unroll
    for (int j = 0; j < 4; ++j) bkc[j] = bias[nb * 128 + wc * 64 + j * 16 + lr];
    #pragma unroll
    for (int i = 0; i < 4; ++i) {
        #pragma unroll
        for (int r = 0; r < 4; ++r) {
            int n = wr * 64 + i * 16 + 4 * g + r;
            int row_glob = mb * 1024 + n * 8 + nb;
            size_t base = ((size_t)(row_glob >> 6) * 4) * 2048 + (size_t)(row_glob & 63) * 32;
            #pragma unroll
            for (int j = 0; j < 4; ++j) {
                int d = wc * 64 + j * 16 + lr;
                float v = geluf(acc[i][j][r] + bkc[j]);
                kblk[base + (size_t)(d >> 5) * 2048 + KP(d & 31)] = f2bf(v);
            }
        }
    }
}

// ---------- h1gemm fused: A = [k,|q-k|,q*k] built on the fly; +qW1 bias; gelu; LN; -> h2A blocked
__global__ __launch_bounds__(256) void h1gemm(
    const u16* __restrict__ kblk, const u16* __restrict__ w1t,
    const u16* __restrict__ qbuf, const float* __restrict__ qw1,
    const float* __restrict__ g1, const float* __restrict__ bb1,
    u16* __restrict__ h2A)
{
    __shared__ __attribute__((aligned(16))) u16 As[2][64 * 32];
    __shared__ float qw1s[2048];
    __shared__ float part[64][4][2];
    const int tid = threadIdx.x, lane = tid & 63, w = tid >> 6;   // w = wc 0..3
    const int lr = lane & 15, g = lane >> 4;
    const int mb = blockIdx.x;    // 0..1023 (64 interaction rows each)
    const int b = mb >> 4;
    for (int i = tid; i < 2048; i += 256) qw1s[i] = qw1[(size_t)b * 2048 + i];
    // q fragments: h = lr&7 fixed per lane
    s16x8 qf[4];
    {
        const u16* qp = qbuf + b * 1024 + (lr & 7) * 128;
        #pragma unroll
        for (int dt = 0; dt < 4; ++dt) {
            ushort4 lo = *(const ushort4*)(qp + dt * 32 + 4 * g);
            ushort4 hi = *(const ushort4*)(qp + dt * 32 + 16 + 4 * g);
            qf[dt] = (s16x8){(short)lo.x, (short)lo.y, (short)lo.z, (short)lo.w,
                             (short)hi.x, (short)hi.y, (short)hi.z, (short)hi.w};
        }
    }
    f32x4 acc[4][4];
    #pragma unroll
    for (int i = 0; i < 4; ++i)
        #pragma unroll
        for (int j = 0; j < 4; ++j) acc[i][j] = (f32x4){0.f, 0.f, 0.f, 0.f};

    auto stageA = [&](int dt, int bi) {
        const u16* ab = kblk + (size_t)(mb * 4 + dt) * 2048;
        async_copy16(ab + w * 512 + lane * 8, &As[bi][w * 512]);
    };
    stageA(0, 0);
    __syncthreads();
    for (int dt = 0; dt < 4; ++dt) {
        int cur = dt & 1;
        if (dt < 3) stageA(dt + 1, cur ^ 1);
        s16x8 kf[4];
        #pragma unroll
        for (int i = 0; i < 4; ++i) kf[i] = *(const s16x8*)&As[cur][(i * 16 + lr) * 32 + g * 8];
        #pragma unroll
        for (int f = 0; f < 3; ++f) {
            s16x8 af[4];
            #pragma unroll
            for (int i = 0; i < 4; ++i)
                af[i] = (f == 0) ? kf[i] : (f == 1) ? feat_abs(kf[i], qf[dt]) : feat_mul(kf[i], qf[dt]);
            s16x8 bfr[4];
            #pragma unroll
            for (int j = 0; j < 4; ++j)
                bfr[j] = *(const s16x8*)&w1t[((size_t)((f * 4 + dt) * 256) + w * 64 + j * 16 + lr) * 32 + g * 8];
            #pragma unroll
            for (int i = 0; i < 4; ++i)
                #pragma unroll
                for (int j = 0; j < 4; ++j) acc[i][j] = MFMA(af[i], bfr[j], acc[i][j]);
        }
        __syncthreads();
    }
    // epilogue: + (qW1+b1) bias, gelu, LN over 256, blocked store for h2
    #pragma unroll
    for (int j = 0; j < 4; ++j) {
        int col = w * 64 + j * 16 + lr;
        #pragma unroll
        for (int i = 0; i < 4; ++i) {
            f32x4 t = acc[i][j];
            #pragma unroll
            for (int r = 0; r < 4; ++r) {
                int hh = (4 * g + r) & 7;
                t[r] = geluf(t[r] + qw1s[hh * 256 + col]);
            }
            acc[i][j] = t;
        }
    }
    float g1c[4], b1c[4];
    #pragma unroll
    for (int j = 0; j < 4; ++j) {
        int col = w * 64 + j * 16 + lr;
        g1c[j] = g1[col]; b1c[j] = bb1[col];
    }
    #pragma unroll
    for (int i = 0; i < 4; ++i)
        #pragma unroll
        for (int r = 0; r < 4; ++r) {
            float a = 0.f, bsq = 0.f;
            #pragma unroll
            for (int j = 0; j < 4; ++j) { float v = acc[i][j][r]; a += v; bsq += v * v; }
            #pragma unroll
            for (int m = 1; m <= 8; m <<= 1) { a += __shfl_xor(a, m, 64); bsq += __shfl_xor(bsq, m, 64); }
            if (lr == 0) {
                int rl = i * 16 + 4 * g + r;
                part[rl][w][0] = a; part[rl][w][1] = bsq;
            }
        }
    __syncthreads();
    #pragma unroll
    for (int i = 0; i < 4; ++i)
        #pragma unroll
        for (int r = 0; r < 4; ++r) {
            int rl = i * 16 + 4 * g + r;
            float S = part[rl][0][0] + part[rl][1][0] + part[rl][2][0] + part[rl][3][0];
            float S2 = part[rl][0][1] + part[rl][1][1] + part[rl][2][1] + part[rl][3][1];
            float mu = S * (1.f / 256.f);
            float var = S2 * (1.f / 256.f) - mu * mu;
            float rs = rsqrtf(var + 1e-5f);
            int row_glob = mb * 64 + rl;
            size_t base = ((size_t)(row_glob >> 7) * 8) * 4096 + (size_t)(row_glob & 127) * 32;
            #pragma unroll
            for (int j = 0; j < 4; ++j) {
                int col = w * 64 + j * 16 + lr;
                float ln = (acc[i][j][r] - mu) * rs * g1c[j] + b1c[j];
                h2A[base + (size_t)(col >> 5) * 4096 + KP(col & 31)] = f2bf(ln);
            }
        }
}

// ---------- h2gemm: h2A[65536x256] @ W2[256x128], gelu + LN + dot(W3) -> scores f32
__global__ __launch_bounds__(256) void h2gemm(
    const u16* __restrict__ gA, const u16* __restrict__ gB,
    const float* __restrict__ b2, const float* __restrict__ g2,
    const float* __restrict__ bb2, const float* __restrict__ W3,
    const float* __restrict__ b3, float* __restrict__ scores)
{
    __shared__ __attribute__((aligned(16))) u16 As[2][128 * 32];
    __shared__ __attribute__((aligned(16))) u16 Bs[2][128 * 32];
    __shared__ float part[128][2][2];
    __shared__ float dotb[128][2];
    const int tid = threadIdx.x, lane = tid & 63, w = tid >> 6;
    const int lr = lane & 15, g = lane >> 4;
    const int wr = w >> 1, wc = w & 1;
    const int mb = blockIdx.x;   // 0..511
    const int NT = 8;
    f32x4 acc[4][4];
    #pragma unroll
    for (int i = 0; i < 4; ++i)
        #pragma unroll
        for (int j = 0; j < 4; ++j) acc[i][j] = (f32x4){0.f, 0.f, 0.f, 0.f};

    auto stage = [&](int t, int bi) {
        const u16* ab = gA + (size_t)(mb * 8 + t) * 4096;
        const u16* bb = gB + (size_t)t * 4096;
        #pragma unroll
        for (int c = w; c < 16; c += 4) {
            if (c < 8) async_copy16(ab + c * 512 + lane * 8, &As[bi][c * 512]);
            else       async_copy16(bb + (c - 8) * 512 + lane * 8, &Bs[bi][(c - 8) * 512]);
        }
    };
    stage(0, 0);
    __syncthreads();
    for (int t = 0; t < NT; ++t) {
        int cur = t & 1;
        if (t + 1 < NT) stage(t + 1, cur ^ 1);
        s16x8 af[4], bfr[4];
        #pragma unroll
        for (int i = 0; i < 4; ++i) af[i] = *(const s16x8*)&As[cur][(wr * 64 + i * 16 + lr) * 32 + g * 8];
        #pragma unroll
        for (int j = 0; j < 4; ++j) bfr[j] = *(const s16x8*)&Bs[cur][(wc * 64 + j * 16 + lr) * 32 + g * 8];
        #pragma unroll
        for (int i = 0; i < 4; ++i)
            #pragma unroll
            for (int j = 0; j < 4; ++j) acc[i][j] = MFMA(af[i], bfr[j], acc[i][j]);
        __syncthreads();
    }
    float bkc[4], g2c[4], b2c[4], w3c[4];
    #pragma unroll
    for (int j = 0; j < 4; ++j) {
        int col = wc * 64 + j * 16 + lr;
        bkc[j] = b2[col]; g2c[j] = g2[col]; b2c[j] = bb2[col]; w3c[j] = W3[col];
    }
    #pragma unroll
    for (int i = 0; i < 4; ++i)
        #pragma unroll
        for (int j = 0; j < 4; ++j) {
            f32x4 t = acc[i][j];
            #pragma unroll
            for (int r = 0; r < 4; ++r) t[r] = geluf(t[r] + bkc[j]);
            acc[i][j] = t;
        }
    #pragma unroll
    for (int i = 0; i < 4; ++i)
        #pragma unroll
        for (int r = 0; r < 4; ++r) {
            float a = 0.f, bsq = 0.f;
            #pragma unroll
            for (int j = 0; j < 4; ++j) { float v = acc[i][j][r]; a += v; bsq += v * v; }
            #pragma unroll
            for (int m = 1; m <= 8; m <<= 1) { a += __shfl_xor(a, m, 64); bsq += __shfl_xor(bsq, m, 64); }
            if (lr == 0) {
                int rl = wr * 64 + i * 16 + 4 * g + r;
                part[rl][wc][0] = a; part[rl][wc][1] = bsq;
            }
        }
    __syncthreads();
    #pragma unroll
    for (int i = 0; i < 4; ++i)
        #pragma unroll
        for (int r = 0; r < 4; ++r) {
            int rl = wr * 64 + i * 16 + 4 * g + r;
            float S = part[rl][0][0] + part[rl][1][0];
            float S2 = part[rl][0][1] + part[rl][1][1];
            float mu = S * (1.f / 128.f);
            float var = S2 * (1.f / 128.f) - mu * mu;
            float rs = rsqrtf(var + 1e-5f);
            float d = 0.f;
            #pragma unroll
            for (int j = 0; j < 4; ++j) {
                float ln = (acc[i][j][r] - mu) * rs * g2c[j] + b2c[j];
                d += ln * w3c[j];
            }
            #pragma unroll
            for (int m = 1; m <= 8; m <<= 1) d += __shfl_xor(d, m, 64);
            if (lr == 0) dotb[rl][wc] = d;
        }
    __syncthreads();
    if (tid < 128) scores[(size_t)mb * 128 + tid] = dotb[tid][0] + dotb[tid][1] + b3[0];
}

// ---------- out[b] = sigmoid( sum_{n,h} score*gate*mask / 8 )
__global__ __launch_bounds__(256) void final_kernel(
    const float* __restrict__ scores, const float* __restrict__ idfs,
    const float* __restrict__ mask, const float* __restrict__ gate_w,
    const float* __restrict__ gate_b, float* __restrict__ outp)
{
    int b = blockIdx.x, tid = threadIdx.x;
    float gw = gate_w[0], gb = gate_b[0];
    float acc = 0.f;
    for (int i = tid; i < 1024; i += 256) {
        int n = i >> 3;
        float lg = log1pf(idfs[b * 128 + n]);
        float gate = 1.f / (1.f + expf(-(lg * gw + gb)));
        acc += scores[b * 1024 + i] * gate * mask[b * 128 + n];
    }
    acc = wave_reduce_sum(acc);
    __shared__ float wsum[4];
    if ((tid & 63) == 0) wsum[tid >> 6] = acc;
    __syncthreads();
    if (tid == 0) {
        float t = wsum[0] + wsum[1] + wsum[2] + wsum[3];
        outp[b] = 1.f / (1.f + expf(-t * 0.125f));
    }
}

extern "C" void kernel_launch(void* const* d_in, const int* in_sizes, int n_in,
                              void* d_out, int out_size, void* d_ws, size_t ws_size,
                              hipStream_t stream) {
    const float* q_emb    = (const float*)d_in[0];
    const float* ent      = (const float*)d_in[1];
    const int*   roles    = (const int*)d_in[2];
    const float* idfs     = (const float*)d_in[3];
    const float* mask     = (const float*)d_in[4];
    const float* role_emb = (const float*)d_in[5];
    const float* ln_f_g   = (const float*)d_in[6];
    const float* ln_f_b   = (const float*)d_in[7];
    const float* Wq       = (const float*)d_in[8];
    const float* bq       = (const float*)d_in[9];
    const float* Wk       = (const float*)d_in[10];
    const float* bk       = (const float*)d_in[11];
    const float* W1       = (const float*)d_in[12];
    const float* b1       = (const float*)d_in[13];
    const float* ln1_g    = (const float*)d_in[14];
    const float* ln1_b    = (const float*)d_in[15];
    const float* W2       = (const float*)d_in[16];
    const float* b2       = (const float*)d_in[17];
    const float* ln2_g    = (const float*)d_in[18];
    const float* ln2_b    = (const float*)d_in[19];
    const float* W3       = (const float*)d_in[20];
    const float* b3       = (const float*)d_in[21];
    const float* gate_w   = (const float*)d_in[22];
    const float* gate_b   = (const float*)d_in[23];
    float* outp = (float*)d_out;

    // workspace layout (bytes) — all regions disjoint, peak ~65.7 MB
    char* ws = (char*)d_ws;
    u16*   nfb    = (u16*)(ws);                          // 12.58 MB
    u16*   kblk   = (u16*)(ws + (size_t)12582912);       // 16.78 MB
    u16*   h2A    = (u16*)(ws + (size_t)29360128);       // 33.55 MB
    u16*   WkT    = (u16*)(ws + (size_t)62914560);       // 1.57 MB
    u16*   W1T    = (u16*)(ws + (size_t)64487424);       // 0.26 MB
    u16*   W2T    = (u16*)(ws + (size_t)64749568);       // 64 KB
    u16*   qbuf   = (u16*)(ws + (size_t)64815104);       // 128 KB
    float* qw1    = (float*)(ws + (size_t)64946176);     // 512 KB
    float* scores = (float*)(ws + (size_t)65470464);     // 256 KB

    prep_w<<<3072, 256, 0, stream>>>(Wk, WkT, 768, 1024, 128);
    prep_w<<<128, 256, 0, stream>>>(W2, W2T, 256, 128, 128);
    prep_w1<<<384, 256, 0, stream>>>(W1, W1T);
    nf_ln_kernel<<<2048, 256, 0, stream>>>(ent, roles, role_emb, ln_f_g, ln_f_b, nfb);
    q_kernel<<<dim3(4, 64), 256, 0, stream>>>(q_emb, Wq, bq, qbuf);
    qw1_kernel<<<512, 256, 0, stream>>>(qbuf, W1, b1, qw1);
    kgemm<<<dim3(8, 64), 256, 0, stream>>>(nfb, WkT, bk, kblk);
    h1gemm<<<1024, 256, 0, stream>>>(kblk, W1T, qbuf, qw1, ln1_g, ln1_b, h2A);
    h2gemm<<<512, 256, 0, stream>>>(h2A, W2T, b2, ln2_g, ln2_b, W3, b3, scores);
    final_kernel<<<64, 256, 0, stream>>>(scores, idfs, mask, gate_w, gate_b, outp);
}